// Round 2
// baseline (668.286 us; speedup 1.0000x reference)
//
#include <hip/hip_runtime.h>

typedef __bf16 bf16_t;
typedef bf16_t bf16x8 __attribute__((ext_vector_type(8)));
typedef bf16_t bf16x4 __attribute__((ext_vector_type(4)));
typedef float f32x4 __attribute__((ext_vector_type(4)));

#define BATCH 16384
#define KDIM  1024
#define NCOLS 9216   // [0,3072) ig | [3072,4096) ii | [4096,5120) ih | [5120,8192) hg | [8192,9216) hh

#define BM 128
#define BN 128
#define BK 32

// ---------------- cast f32 -> bf16 (vectorized float4 -> bf16x4) ----------------
__global__ __launch_bounds__(256) void cast_f32_bf16(const float* __restrict__ src,
                                                     bf16_t* __restrict__ dst, int n4) {
  int i = blockIdx.x * 256 + threadIdx.x;
  if (i < n4) {
    float4 v = reinterpret_cast<const float4*>(src)[i];
    bf16x4 o;
    o[0] = (bf16_t)v.x; o[1] = (bf16_t)v.y; o[2] = (bf16_t)v.z; o[3] = (bf16_t)v.w;
    reinterpret_cast<bf16x4*>(dst)[i] = o;
  }
}

// ---------------- bias concat into bcat[9216] ----------------
__global__ __launch_bounds__(256)
void concat_bias(const float* __restrict__ b_ig, const float* __restrict__ b_ii,
                 const float* __restrict__ b_ih, const float* __restrict__ b_hg,
                 const float* __restrict__ b_hh, float* __restrict__ bcat) {
  int i = blockIdx.x * 256 + threadIdx.x;
  if (i >= NCOLS) return;
  float v;
  if      (i < 3072) v = b_ig[i];
  else if (i < 4096) v = b_ii[i - 3072];
  else if (i < 5120) v = b_ih[i - 4096];
  else if (i < 8192) v = b_hg[i - 5120];
  else               v = b_hh[i - 8192];
  bcat[i] = v;
}

// ---------------- fused GEMM: preLN[r, 0:9216] = act @ Wcat^T + bcat (bf16 out) ----------------
// m97 structure: 128x128 tile, BK=32, 4 waves (2x2), 4x4 16x16x32 fragments per wave,
// double-buffered LDS staged via global_load_lds width=16.
__global__ __launch_bounds__(256)
void gemm_preln(const bf16_t* __restrict__ inpb, const bf16_t* __restrict__ hidb,
                const bf16_t* __restrict__ Wcat, const float* __restrict__ bcat,
                bf16_t* __restrict__ preLN)
{
  __shared__ alignas(16) bf16_t As[2][BM * BK];
  __shared__ alignas(16) bf16_t Bs[2][BN * BK];
  const int tid  = threadIdx.x;
  const int wid  = tid >> 6;        // wave id 0..3
  const int lane = tid & 63;
  const int row0 = blockIdx.x * BM;           // row within chunk
  const int col0 = blockIdx.y * BN;           // global column in [0,9216)
  const bf16_t* __restrict__ act = (col0 < 5120) ? inpb : hidb;
  const bf16_t* __restrict__ wgt = Wcat + (size_t)col0 * KDIM;

  f32x4 acc[4][4] = {};

  const int wr = wid >> 1, wc = wid & 1; // wave tile 64x64 within 128x128
  const int fr = lane & 15;              // fragment row (A) / col (B)
  const int kg = lane >> 4;              // k-chunk 0..3 (8 elems each)

  auto stage = [&](int buf, int kt) {
    const int k0 = kt * BK;
    #pragma unroll
    for (int c = 0; c < 2; ++c) {
      const int e = c * 2048 + tid * 8;     // flat bf16 elem in [128][32] tile
      const int r = e >> 5, kk = e & 31;
      const bf16_t* ga = act + (size_t)(row0 + r) * KDIM + (k0 + kk);
      const bf16_t* gb = wgt + (size_t)r * KDIM + (k0 + kk);
      __builtin_amdgcn_global_load_lds(
          (const __attribute__((address_space(1))) unsigned int*)ga,
          (__attribute__((address_space(3))) unsigned int*)&As[buf][c * 2048 + wid * 512],
          16, 0, 0);
      __builtin_amdgcn_global_load_lds(
          (const __attribute__((address_space(1))) unsigned int*)gb,
          (__attribute__((address_space(3))) unsigned int*)&Bs[buf][c * 2048 + wid * 512],
          16, 0, 0);
    }
  };

  auto compute = [&](int buf) {
    bf16x8 a[4], b[4];
    #pragma unroll
    for (int m = 0; m < 4; ++m)
      a[m] = *(const bf16x8*)&As[buf][(wr * 64 + m * 16 + fr) * BK + kg * 8];
    #pragma unroll
    for (int n = 0; n < 4; ++n)
      b[n] = *(const bf16x8*)&Bs[buf][(wc * 64 + n * 16 + fr) * BK + kg * 8];
    #pragma unroll
    for (int m = 0; m < 4; ++m)
      #pragma unroll
      for (int n = 0; n < 4; ++n)
        acc[m][n] = __builtin_amdgcn_mfma_f32_16x16x32_bf16(a[m], b[n], acc[m][n], 0, 0, 0);
  };

  stage(0, 0);
  __syncthreads();
  int cur = 0;
  const int NT = KDIM / BK;  // 32
  for (int t = 0; t < NT; ++t) {
    if (t + 1 < NT) stage(cur ^ 1, t + 1);
    compute(cur);
    __syncthreads();
    cur ^= 1;
  }

  // epilogue: add bias, store bf16 pre-LN
  const int orow = row0 + wr * 64;
  const int ocol = col0 + wc * 64;
  #pragma unroll
  for (int n = 0; n < 4; ++n) {
    const int col = ocol + n * 16 + fr;
    const float bias = bcat[col];
    #pragma unroll
    for (int m = 0; m < 4; ++m) {
      const int rbase = orow + m * 16 + kg * 4;
      #pragma unroll
      for (int j = 0; j < 4; ++j)
        preLN[(size_t)(rbase + j) * NCOLS + col] = (bf16_t)(acc[m][n][j] + bias);
    }
  }
}

// ---------------- fused LN + gates + combine, one block per row ----------------
__global__ __launch_bounds__(256)
void ln_combine(const bf16_t* __restrict__ preLN, const float* __restrict__ hidden,
                const float* __restrict__ g_ig, const float* __restrict__ be_ig,
                const float* __restrict__ g_hg, const float* __restrict__ be_hg,
                const float* __restrict__ g_ii, const float* __restrict__ be_ii,
                const float* __restrict__ g_ih, const float* __restrict__ be_ih,
                const float* __restrict__ g_hh, const float* __restrict__ be_hh,
                float* __restrict__ out)
{
  __shared__ alignas(16) bf16_t rowbuf[NCOLS];
  __shared__ float red[8];
  __shared__ float stats[10]; // mu[0..4], rstd[5..9]
  const int tid = threadIdx.x;
  const size_t row = blockIdx.x;   // row within chunk
  const bf16_t* __restrict__ src = preLN + row * NCOLS;

  // load row: 9216 bf16 = 1152 x 16B
  for (int i = tid; i < 1152; i += 256)
    *(uint4*)&rowbuf[i * 8] = *(const uint4*)&src[i * 8];
  __syncthreads();

  const int seg_lo[5] = {0, 3072, 4096, 5120, 8192};
  const int seg_n[5]  = {3072, 1024, 1024, 3072, 1024};
  for (int s = 0; s < 5; ++s) {
    float s1 = 0.f, s2 = 0.f;
    const int lo = seg_lo[s], hi = seg_lo[s] + seg_n[s];
    for (int i = lo + tid; i < hi; i += 256) {
      float x = (float)rowbuf[i];
      s1 += x; s2 += x * x;
    }
    #pragma unroll
    for (int off = 32; off; off >>= 1) {
      s1 += __shfl_down(s1, off);
      s2 += __shfl_down(s2, off);
    }
    if ((tid & 63) == 0) { red[tid >> 6] = s1; red[4 + (tid >> 6)] = s2; }
    __syncthreads();
    if (tid == 0) {
      float t1 = red[0] + red[1] + red[2] + red[3];
      float t2 = red[4] + red[5] + red[6] + red[7];
      float mu = t1 / seg_n[s];
      float var = t2 / seg_n[s] - mu * mu;
      stats[s] = mu;
      stats[5 + s] = rsqrtf(var + 1e-5f);
    }
    __syncthreads();
  }

  const float mu0 = stats[0], r0 = stats[5];
  const float mu1 = stats[1], r1 = stats[6];
  const float mu2 = stats[2], r2 = stats[7];
  const float mu3 = stats[3], r3 = stats[8];
  const float mu4 = stats[4], r4 = stats[9];
  const float* __restrict__ hrow = hidden + row * 1024;

  for (int c = tid; c < 1024; c += 256) {
    float x_igr = (float)rowbuf[c];
    float x_igz = (float)rowbuf[c + 1024];
    float x_igg = (float)rowbuf[c + 2048];
    float x_ii  = (float)rowbuf[3072 + c];
    float x_ih  = (float)rowbuf[4096 + c];
    float x_hgr = (float)rowbuf[5120 + c];
    float x_hgz = (float)rowbuf[6144 + c];
    float x_hgg = (float)rowbuf[7168 + c];
    float x_hh  = (float)rowbuf[8192 + c];

    float pr = (x_igr - mu0) * r0 * g_ig[c]        + be_ig[c]
             + (x_hgr - mu3) * r3 * g_hg[c]        + be_hg[c];
    float pz = (x_igz - mu0) * r0 * g_ig[c + 1024] + be_ig[c + 1024]
             + (x_hgz - mu3) * r3 * g_hg[c + 1024] + be_hg[c + 1024];
    float pg = (x_igg - mu0) * r0 * g_ig[c + 2048] + be_ig[c + 2048]
             + (x_hgg - mu3) * r3 * g_hg[c + 2048] + be_hg[c + 2048];

    float rr = 1.f / (1.f + __expf(-pr));
    float zz = 1.f / (1.f + __expf(-pz));
    float gg = 1.f / (1.f + __expf(-pg));

    float Hx = (x_ii - mu1) * r1 * g_ii[c] + be_ii[c];
    float xh = (x_ih - mu2) * r2 * g_ih[c] + be_ih[c];
    float hh = (x_hh - mu4) * r4 * g_hh[c] + be_hh[c];

    float hm = tanhf((1.f - rr) * xh + rr * hh);
    float h  = hrow[c];
    out[row * 1024 + c] = ((1.f - zz) * h + zz * hm) * (1.f - gg) + gg * Hx;
  }
}

extern "C" void kernel_launch(void* const* d_in, const int* in_sizes, int n_in,
                              void* d_out, int out_size, void* d_ws, size_t ws_size,
                              hipStream_t stream) {
  const float* inp      = (const float*)d_in[0];
  const float* hidden   = (const float*)d_in[1];
  const float* W_i2gate = (const float*)d_in[2];
  const float* b_i2gate = (const float*)d_in[3];
  const float* W_h2gate = (const float*)d_in[4];
  const float* b_h2gate = (const float*)d_in[5];
  const float* W_i2i    = (const float*)d_in[6];
  const float* b_i2i    = (const float*)d_in[7];
  const float* W_i2h    = (const float*)d_in[8];
  const float* b_i2h    = (const float*)d_in[9];
  const float* W_h2h    = (const float*)d_in[10];
  const float* b_h2h    = (const float*)d_in[11];
  const float* g_ig  = (const float*)d_in[12];
  const float* be_ig = (const float*)d_in[13];
  const float* g_hg  = (const float*)d_in[14];
  const float* be_hg = (const float*)d_in[15];
  const float* g_ii  = (const float*)d_in[16];
  const float* be_ii = (const float*)d_in[17];
  const float* g_ih  = (const float*)d_in[18];
  const float* be_ih = (const float*)d_in[19];
  const float* g_hh  = (const float*)d_in[20];
  const float* be_hh = (const float*)d_in[21];
  float* out = (float*)d_out;

  // ---- workspace layout (adaptive to ws_size) ----
  // persistent: Wcat (9216x1024 bf16 = 18,874,368 B) + bcat (36,864 B)
  const size_t WCAT_B  = (size_t)NCOLS * KDIM * 2;     // 18,874,368
  const size_t BCAT_B  = (size_t)NCOLS * 4;            // 36,864
  const size_t FIXED_B = WCAT_B + BCAT_B;              // 18,911,232 (256-aligned)
  // per-row dynamic: inpb 2048 B + hidb 2048 B + preLN 18,432 B
  const size_t PER_ROW = 2048 + 2048 + 18432;          // 22,528

  if (ws_size < FIXED_B + PER_ROW * 128) return;       // visibly fail (poisoned out), no OOB

  char* ws = (char*)d_ws;
  bf16_t* Wcat = (bf16_t*)ws;
  float*  bcat = (float*)(ws + WCAT_B);
  char*   dyn  = ws + FIXED_B;

  size_t max_rows = (ws_size - FIXED_B) / PER_ROW;
  int chunk = (int)((max_rows / 128) * 128);
  if (chunk > BATCH) chunk = BATCH;

  bf16_t* inpb  = (bf16_t*)dyn;
  bf16_t* hidb  = (bf16_t*)(dyn + (size_t)chunk * 2048);
  bf16_t* preLN = (bf16_t*)(dyn + (size_t)chunk * 4096);

  // ---- weights cast + bias concat (once) ----
  {
    int n4g = 3072 * 1024 / 4, n4s = 1024 * 1024 / 4;
    cast_f32_bf16<<<(n4g + 255) / 256, 256, 0, stream>>>(W_i2gate, Wcat, n4g);
    cast_f32_bf16<<<(n4s + 255) / 256, 256, 0, stream>>>(W_i2i, Wcat + 3072 * 1024, n4s);
    cast_f32_bf16<<<(n4s + 255) / 256, 256, 0, stream>>>(W_i2h, Wcat + 4096 * 1024, n4s);
    cast_f32_bf16<<<(n4g + 255) / 256, 256, 0, stream>>>(W_h2gate, Wcat + 5120 * 1024, n4g);
    cast_f32_bf16<<<(n4s + 255) / 256, 256, 0, stream>>>(W_h2h, Wcat + 8192 * 1024, n4s);
    concat_bias<<<(NCOLS + 255) / 256, 256, 0, stream>>>(b_i2gate, b_i2i, b_i2h,
                                                         b_h2gate, b_h2h, bcat);
  }

  // ---- chunked: cast acts -> GEMM -> LN+combine ----
  for (int r0 = 0; r0 < BATCH; r0 += chunk) {
    int cr = BATCH - r0;
    if (cr > chunk) cr = chunk;
    int n4 = cr * KDIM / 4;
    cast_f32_bf16<<<(n4 + 255) / 256, 256, 0, stream>>>(inp + (size_t)r0 * KDIM, inpb, n4);
    cast_f32_bf16<<<(n4 + 255) / 256, 256, 0, stream>>>(hidden + (size_t)r0 * KDIM, hidb, n4);

    dim3 ggrid(cr / BM, NCOLS / BN);
    gemm_preln<<<ggrid, 256, 0, stream>>>(inpb, hidb, Wcat, bcat, preLN);

    ln_combine<<<cr, 256, 0, stream>>>(preLN, hidden + (size_t)r0 * KDIM,
                                       g_ig, be_ig, g_hg, be_hg,
                                       g_ii, be_ii, g_ih, be_ih, g_hh, be_hh,
                                       out + (size_t)r0 * KDIM);
  }
}